// Round 1
// baseline (2632.084 us; speedup 1.0000x reference)
//
#include <hip/hip_runtime.h>
#include <math.h>

#define Bg   64
#define Mg   100
#define Ng   6400
#define Eg   102400
#define Hh   4
#define Dd   512
#define HDd  2048
#define EMBd 768
#define IMGd 1024
#define EPSc 1e-5f

__device__ __forceinline__ float eluf(float x) { return x > 0.f ? x : expm1f(x); }

// ---------------------------------------------------------------------------
// Generic fp32 GEMM: C[M,N] = act(A[M,K] @ W[N,K]^T + bias)
// 64x64 tile, 256 threads, 4x4 per thread, K-tile 16. K must be %16.
// act: 0 = none, 1 = elu
// ---------------------------------------------------------------------------
__global__ __launch_bounds__(256)
void gemm_nt(const float* __restrict__ A, const float* __restrict__ W,
             const float* __restrict__ bias, float* __restrict__ C,
             int M, int N, int K, int act)
{
    __shared__ float As[16 * 68];
    __shared__ float Ws[16 * 68];
    const int tid = threadIdx.x;
    const int tx = tid & 15, ty = tid >> 4;
    const int bm = blockIdx.y * 64, bn = blockIdx.x * 64;
    const int lrow = tid >> 2;
    const int lk4  = (tid & 3) << 2;
    const int arow = bm + lrow;
    const int wrow = bn + lrow;
    const float* Aptr = A + (size_t)arow * K + lk4;
    const float* Wptr = W + (size_t)wrow * K + lk4;
    float acc[4][4] = {{0.f,0.f,0.f,0.f},{0.f,0.f,0.f,0.f},{0.f,0.f,0.f,0.f},{0.f,0.f,0.f,0.f}};

    for (int k0 = 0; k0 < K; k0 += 16) {
        float4 av = make_float4(0.f,0.f,0.f,0.f);
        float4 wv = make_float4(0.f,0.f,0.f,0.f);
        if (arow < M) av = *(const float4*)(Aptr + k0);
        if (wrow < N) wv = *(const float4*)(Wptr + k0);
        As[(lk4+0)*68 + lrow] = av.x;
        As[(lk4+1)*68 + lrow] = av.y;
        As[(lk4+2)*68 + lrow] = av.z;
        As[(lk4+3)*68 + lrow] = av.w;
        Ws[(lk4+0)*68 + lrow] = wv.x;
        Ws[(lk4+1)*68 + lrow] = wv.y;
        Ws[(lk4+2)*68 + lrow] = wv.z;
        Ws[(lk4+3)*68 + lrow] = wv.w;
        __syncthreads();
#pragma unroll
        for (int kk = 0; kk < 16; ++kk) {
            float4 a = *(const float4*)&As[kk*68 + (ty<<2)];
            float4 w = *(const float4*)&Ws[kk*68 + (tx<<2)];
            acc[0][0] += a.x*w.x; acc[0][1] += a.x*w.y; acc[0][2] += a.x*w.z; acc[0][3] += a.x*w.w;
            acc[1][0] += a.y*w.x; acc[1][1] += a.y*w.y; acc[1][2] += a.y*w.z; acc[1][3] += a.y*w.w;
            acc[2][0] += a.z*w.x; acc[2][1] += a.z*w.y; acc[2][2] += a.z*w.z; acc[2][3] += a.z*w.w;
            acc[3][0] += a.w*w.x; acc[3][1] += a.w*w.y; acc[3][2] += a.w*w.z; acc[3][3] += a.w*w.w;
        }
        __syncthreads();
    }

#pragma unroll
    for (int i = 0; i < 4; ++i) {
        int row = bm + (ty<<2) + i;
        int col = bn + (tx<<2);
        if (row < M && col < N) {
            float4 v;
            v.x = acc[i][0]; v.y = acc[i][1]; v.z = acc[i][2]; v.w = acc[i][3];
            if (bias) { v.x += bias[col]; v.y += bias[col+1]; v.z += bias[col+2]; v.w += bias[col+3]; }
            if (act == 1) { v.x = eluf(v.x); v.y = eluf(v.y); v.z = eluf(v.z); v.w = eluf(v.w); }
            *(float4*)(C + (size_t)row * N + col) = v;
        }
    }
}

// ---------------------------------------------------------------------------
// BatchNorm (eval) over columns: y[r,c] = (x[r,c]-m[c])*rsqrt(v[c]+eps)*g[c]+b[c]
// ---------------------------------------------------------------------------
__global__ void bn_col(const float* __restrict__ x, const float* __restrict__ g,
                       const float* __restrict__ b, const float* __restrict__ m,
                       const float* __restrict__ v, float* __restrict__ y,
                       int rows, int cols)
{
    int i = blockIdx.x * 256 + threadIdx.x;
    if (i >= rows * cols) return;
    int c = i % cols;
    float inv = rsqrtf(v[c] + EPSc);
    y[i] = (x[i] - m[c]) * inv * g[c] + b[c];
}

// BN over node-position p = n % 100 (BN3 channel dim)
__global__ void bn_node(const float* __restrict__ x, const float* __restrict__ g,
                        const float* __restrict__ b, const float* __restrict__ m,
                        const float* __restrict__ v, float* __restrict__ y,
                        int total, int Cdim)
{
    int i = blockIdx.x * 256 + threadIdx.x;
    if (i >= total) return;
    int n = i / Cdim;
    int p = n % Mg;
    float inv = rsqrtf(v[p] + EPSc);
    y[i] = (x[i] - m[p]) * inv * g[p] + b[p];
}

// ---------------------------------------------------------------------------
// CSR build by dst
// ---------------------------------------------------------------------------
__global__ void zero_i32(int* __restrict__ p, int n)
{
    int i = blockIdx.x * 256 + threadIdx.x;
    if (i < n) p[i] = 0;
}

__global__ void count_dst(const int* __restrict__ dst, int* __restrict__ counts, int E)
{
    int i = blockIdx.x * 256 + threadIdx.x;
    if (i < E) atomicAdd(&counts[dst[i]], 1);
}

__global__ __launch_bounds__(1024)
void scan_excl(const int* __restrict__ counts, int* __restrict__ offs,
               int* __restrict__ cursor, int n)
{
    __shared__ int sm[1024];
    __shared__ int carry;
    if (threadIdx.x == 0) carry = 0;
    __syncthreads();
    for (int base = 0; base < n; base += 1024) {
        int i = base + (int)threadIdx.x;
        int v = (i < n) ? counts[i] : 0;
        sm[threadIdx.x] = v;
        __syncthreads();
        for (int o = 1; o < 1024; o <<= 1) {
            int t = (threadIdx.x >= (unsigned)o) ? sm[threadIdx.x - o] : 0;
            __syncthreads();
            sm[threadIdx.x] += t;
            __syncthreads();
        }
        int incl = sm[threadIdx.x];
        int myc = carry;
        if (i < n) {
            int ex = myc + incl - v;
            offs[i] = ex;
            cursor[i] = ex;
        }
        __syncthreads();
        if (threadIdx.x == 1023) carry = myc + sm[1023];
        __syncthreads();
    }
    if (threadIdx.x == 0) offs[n] = carry;
}

__global__ void scatter_edges(const int* __restrict__ dst, int* __restrict__ cursor,
                              int* __restrict__ eid, int E)
{
    int i = blockIdx.x * 256 + threadIdx.x;
    if (i < E) {
        int p = atomicAdd(&cursor[dst[i]], 1);
        eid[p] = i;
    }
}

// ---------------------------------------------------------------------------
// el[n,h] = sum_d H[n, h*512+d] * al[h,d] ; er likewise. One wave per (n,h).
// ---------------------------------------------------------------------------
__global__ __launch_bounds__(256)
void elr_kernel(const float* __restrict__ Hm, const float* __restrict__ al,
                const float* __restrict__ ar, float* __restrict__ el,
                float* __restrict__ er)
{
    int wid = threadIdx.x >> 6, lane = threadIdx.x & 63;
    int g = (blockIdx.x << 2) + wid;          // (n,h) pair id, < Ng*Hh
    int n = g >> 2, h = g & 3;
    const float* hp  = Hm + ((size_t)n << 11) + (h << 9);
    const float* alp = al + (h << 9);
    const float* arp = ar + (h << 9);
    float se = 0.f, sr = 0.f;
    for (int d = lane; d < Dd; d += 64) {
        float x = hp[d];
        se += x * alp[d];
        sr += x * arp[d];
    }
#pragma unroll
    for (int o = 32; o > 0; o >>= 1) {
        se += __shfl_down(se, o, 64);
        sr += __shfl_down(sr, o, 64);
    }
    if (lane == 0) { el[g] = se; er[g] = sr; }
}

// ---------------------------------------------------------------------------
// GAT aggregation: one block (256 thr) per dst node. Online softmax over
// incoming edges per head, accumulate sum_e w_e * H[src_e, :], normalize,
// add bias. Each thread owns 8 of the 2048 dims (strided by 256).
// ---------------------------------------------------------------------------
__global__ __launch_bounds__(256)
void gat_agg(const float* __restrict__ Hm, const float* __restrict__ el,
             const float* __restrict__ er, const int* __restrict__ src,
             const int* __restrict__ offs, const int* __restrict__ eid,
             const float* __restrict__ bias, float* __restrict__ out)
{
    int n = blockIdx.x;
    int tid = threadIdx.x;
    int beg = offs[n], end = offs[n + 1];
    int deg = end - beg;

    if (deg == 0) {
#pragma unroll
        for (int j = 0; j < 8; ++j) {
            int d = tid + (j << 8);
            out[((size_t)n << 11) + d] = bias[d];
        }
        return;
    }

    __shared__ float m_sh[4], s_sh[4], al_sh[4];
    __shared__ int   src_sh[128];
    __shared__ float logit_sh[512];
    __shared__ float w_sh[512];

    if (tid < 4) { m_sh[tid] = -INFINITY; s_sh[tid] = 0.f; }
    float acc[8] = {0.f,0.f,0.f,0.f,0.f,0.f,0.f,0.f};
    __syncthreads();

    for (int c0 = 0; c0 < deg; c0 += 128) {
        int cnt = min(128, deg - c0);
        for (int i = tid; i < cnt; i += 256) src_sh[i] = src[eid[beg + c0 + i]];
        __syncthreads();
        for (int idx = tid; idx < (cnt << 2); idx += 256) {
            int i = idx >> 2, h = idx & 3;
            float x = el[(src_sh[i] << 2) + h] + er[(n << 2) + h];
            logit_sh[idx] = x > 0.f ? x : 0.2f * x;
        }
        __syncthreads();
        if (tid < 4) {
            float cm = -INFINITY;
            for (int i = 0; i < cnt; ++i) cm = fmaxf(cm, logit_sh[(i << 2) + tid]);
            float mn = fmaxf(m_sh[tid], cm);
            al_sh[tid] = expf(m_sh[tid] - mn);   // 0 when m was -inf
            m_sh[tid] = mn;
        }
        __syncthreads();
        for (int idx = tid; idx < (cnt << 2); idx += 256)
            w_sh[idx] = expf(logit_sh[idx] - m_sh[idx & 3]);
        __syncthreads();
        if (tid < 4) {
            float cs = 0.f;
            for (int i = 0; i < cnt; ++i) cs += w_sh[(i << 2) + tid];
            s_sh[tid] = s_sh[tid] * al_sh[tid] + cs;
        }
#pragma unroll
        for (int j = 0; j < 8; ++j) acc[j] *= al_sh[j >> 1];
        for (int i = 0; i < cnt; ++i) {
            const float* hp = Hm + ((size_t)src_sh[i] << 11);
#pragma unroll
            for (int j = 0; j < 8; ++j)
                acc[j] += w_sh[(i << 2) + (j >> 1)] * hp[tid + (j << 8)];
        }
        __syncthreads();
    }

#pragma unroll
    for (int j = 0; j < 8; ++j) {
        int d = tid + (j << 8);
        out[((size_t)n << 11) + d] = acc[j] / s_sh[j >> 1] + bias[d];
    }
}

// ---------------------------------------------------------------------------
// pos branch: per (node, out-channel): BN(per node-pos) -> @ W[32,4]^T -> elu
// ---------------------------------------------------------------------------
__global__ void pos_kernel(const float* __restrict__ pos, const float* __restrict__ g,
                           const float* __restrict__ b, const float* __restrict__ m,
                           const float* __restrict__ v, const float* __restrict__ W,
                           const float* __restrict__ bias, float* __restrict__ out)
{
    int i = blockIdx.x * 256 + threadIdx.x;
    if (i >= Ng * 32) return;
    int n = i >> 5, o = i & 31;
    int p = n % Mg;
    float inv = rsqrtf(v[p] + EPSc);
    float sc = inv * g[p];
    float sh = b[p] - m[p] * sc;
    float acc = bias[o];
#pragma unroll
    for (int c = 0; c < 4; ++c) {
        float xv = pos[(n << 2) + c] * sc + sh;
        acc += xv * W[(o << 2) + c];
    }
    out[i] = eluf(acc);
}

// mean over 100 nodes of concat([hg 480, pg 32]) -> hf[64,512]
__global__ void mean_kernel(const float* __restrict__ hg, const float* __restrict__ pg,
                            float* __restrict__ hf)
{
    int i = blockIdx.x * 256 + threadIdx.x;   // < 64*512
    int bb = i >> 9, c = i & 511;
    float s = 0.f;
    if (c < 480) {
        const float* p = hg + (size_t)bb * Mg * 480 + c;
        for (int mm = 0; mm < Mg; ++mm) s += p[mm * 480];
    } else {
        const float* p = pg + (size_t)bb * Mg * 32 + (c - 480);
        for (int mm = 0; mm < Mg; ++mm) s += p[mm * 32];
    }
    hf[i] = s * 0.01f;
}

// final: BN(concat[x,hf,ft]) @ final_W[2,1536]^T + final_b. One block per graph.
__global__ __launch_bounds__(256)
void final_kernel(const float* __restrict__ x, const float* __restrict__ hf,
                  const float* __restrict__ ft, const float* __restrict__ g,
                  const float* __restrict__ b, const float* __restrict__ m,
                  const float* __restrict__ v, const float* __restrict__ W,
                  const float* __restrict__ bias, float* __restrict__ out)
{
    int bb = blockIdx.x;
    int tid = threadIdx.x;
    float a0 = 0.f, a1 = 0.f;
    for (int c = tid; c < 1536; c += 256) {
        float xv = (c < 512) ? x[bb * 512 + c]
                 : (c < 1024) ? hf[bb * 512 + (c - 512)]
                              : ft[bb * 512 + (c - 1024)];
        float z = (xv - m[c]) * rsqrtf(v[c] + EPSc) * g[c] + b[c];
        a0 += z * W[c];
        a1 += z * W[1536 + c];
    }
    __shared__ float r0[256], r1[256];
    r0[tid] = a0; r1[tid] = a1;
    __syncthreads();
    for (int o = 128; o > 0; o >>= 1) {
        if (tid < o) { r0[tid] += r0[tid + o]; r1[tid] += r1[tid + o]; }
        __syncthreads();
    }
    if (tid == 0) {
        out[bb * 2 + 0] = r0[0] + bias[0];
        out[bb * 2 + 1] = r1[0] + bias[1];
    }
}

// ---------------------------------------------------------------------------
extern "C" void kernel_launch(void* const* d_in, const int* in_sizes, int n_in,
                              void* d_out, int out_size, void* d_ws, size_t ws_size,
                              hipStream_t stream)
{
    (void)in_sizes; (void)n_in; (void)out_size; (void)ws_size;

    const float* img   = (const float*)d_in[0];
    const float* ftxt  = (const float*)d_in[1];
    const float* unixe = (const float*)d_in[2];
    const float* pos   = (const float*)d_in[3];
    const int*   src   = (const int*)  d_in[4];
    const int*   dst   = (const int*)  d_in[5];
    const float* g1W   = (const float*)d_in[6];
    const float* g1al  = (const float*)d_in[7];
    const float* g1ar  = (const float*)d_in[8];
    const float* g1b   = (const float*)d_in[9];
    const float* g2W   = (const float*)d_in[10];
    const float* g2al  = (const float*)d_in[11];
    const float* g2ar  = (const float*)d_in[12];
    const float* g2b   = (const float*)d_in[13];
    const float* fcW   = (const float*)d_in[14];
    const float* fcb   = (const float*)d_in[15];
    const float* hidW  = (const float*)d_in[16];
    const float* hidb  = (const float*)d_in[17];
    const float* btg   = (const float*)d_in[18];
    const float* btb   = (const float*)d_in[19];
    const float* btm   = (const float*)d_in[20];
    const float* btv   = (const float*)d_in[21];
    const float* ftW   = (const float*)d_in[22];
    const float* ftbi  = (const float*)d_in[23];
    const float* swg   = (const float*)d_in[24];
    const float* swb   = (const float*)d_in[25];
    const float* swm   = (const float*)d_in[26];
    const float* swv   = (const float*)d_in[27];
    const float* swW   = (const float*)d_in[28];
    const float* swbi  = (const float*)d_in[29];
    const float* bgg   = (const float*)d_in[30];
    const float* bgb   = (const float*)d_in[31];
    const float* bgm   = (const float*)d_in[32];
    const float* bgv   = (const float*)d_in[33];
    const float* fgW   = (const float*)d_in[34];
    const float* fgb   = (const float*)d_in[35];
    const float* bbgp  = (const float*)d_in[36];
    const float* bbbp  = (const float*)d_in[37];
    const float* bbmp  = (const float*)d_in[38];
    const float* bbvp  = (const float*)d_in[39];
    const float* fbW   = (const float*)d_in[40];
    const float* fbb   = (const float*)d_in[41];
    const float* fng   = (const float*)d_in[42];
    const float* fnb   = (const float*)d_in[43];
    const float* fnm   = (const float*)d_in[44];
    const float* fnv   = (const float*)d_in[45];
    const float* fiW   = (const float*)d_in[46];
    const float* fib   = (const float*)d_in[47];
    float* out = (float*)d_out;

    // workspace layout
    float* ws  = (float*)d_ws;
    float* fA  = ws;                              // [6400,2048]
    float* fB  = fA + (size_t)Ng * HDd;           // [6400,2048]
    float* fC  = fB + (size_t)Ng * HDd;           // [6400,512]
    float* fD  = fC + (size_t)Ng * Dd;            // [6400,512]
    float* fE  = fD + (size_t)Ng * Dd;            // [6400,480]
    float* pg  = fE + (size_t)Ng * 480;           // [6400,32]
    float* el  = pg + (size_t)Ng * 32;            // [6400,4]
    float* er  = el + (size_t)Ng * Hh;            // [6400,4]
    float* xb  = er + (size_t)Ng * Hh;            // [64,512]
    float* ftb = xb + Bg * Dd;                    // [64,512]
    float* hf  = ftb + Bg * Dd;                   // [64,512]
    float* ti  = hf + Bg * Dd;                    // [64,1024]
    float* tt  = ti + Bg * IMGd;                  // [64,768]
    int* counts = (int*)(tt + Bg * EMBd);         // [6400]
    int* offs   = counts + Ng;                    // [6401]
    int* cursor = offs + Ng + 1;                  // [6400]
    int* eid    = cursor + Ng;                    // [102400]

    // image branch: x = elu(BN(img) @ swinfc_W^T + b)
    bn_col<<<(Bg*IMGd + 255)/256, 256, 0, stream>>>(img, swg, swb, swm, swv, ti, Bg, IMGd);
    gemm_nt<<<dim3(8, 1), 256, 0, stream>>>(ti, swW, swbi, xb, Bg, Dd, IMGd, 1);

    // text branch
    bn_col<<<(Bg*EMBd + 255)/256, 256, 0, stream>>>(ftxt, btg, btb, btm, btv, tt, Bg, EMBd);
    gemm_nt<<<dim3(8, 1), 256, 0, stream>>>(tt, ftW, ftbi, ftb, Bg, Dd, EMBd, 1);

    // CSR by dst
    zero_i32<<<(Ng + 255)/256, 256, 0, stream>>>(counts, Ng);
    count_dst<<<(Eg + 255)/256, 256, 0, stream>>>(dst, counts, Eg);
    scan_excl<<<1, 1024, 0, stream>>>(counts, offs, cursor, Ng);
    scatter_edges<<<(Eg + 255)/256, 256, 0, stream>>>(dst, cursor, eid, Eg);

    // GAT layer 1
    gemm_nt<<<dim3(HDd/64, Ng/64), 256, 0, stream>>>(unixe, g1W, nullptr, fA, Ng, HDd, EMBd, 0);
    elr_kernel<<<Ng, 256, 0, stream>>>(fA, g1al, g1ar, el, er);
    gat_agg<<<Ng, 256, 0, stream>>>(fA, el, er, src, offs, eid, g1b, fB);

    // GAT layer 2
    gemm_nt<<<dim3(HDd/64, Ng/64), 256, 0, stream>>>(fB, g2W, nullptr, fA, Ng, HDd, HDd, 0);
    elr_kernel<<<Ng, 256, 0, stream>>>(fA, g2al, g2ar, el, er);
    gat_agg<<<Ng, 256, 0, stream>>>(fA, el, er, src, offs, eid, g2b, fB);

    // fc: [6400,2048] -> [6400,512], elu
    gemm_nt<<<dim3(Dd/64, Ng/64), 256, 0, stream>>>(fB, fcW, fcb, fC, Ng, Dd, HDd, 1);

    // 8 hidden layers, ping-pong fC<->fD
    float* cur = fC; float* nxt = fD;
    for (int i = 0; i < 8; ++i) {
        gemm_nt<<<dim3(Dd/64, Ng/64), 256, 0, stream>>>(
            cur, hidW + (size_t)i * Dd * Dd, hidb + (size_t)i * Dd, nxt, Ng, Dd, Dd, 1);
        float* t = cur; cur = nxt; nxt = t;
    }
    // result back in fC (cur == fC after 8 swaps)

    // BN over node position, then fc_gat -> [6400,480], elu
    bn_node<<<(Ng*Dd + 255)/256, 256, 0, stream>>>(cur, bgg, bgb, bgm, bgv, nxt, Ng*Dd, Dd);
    gemm_nt<<<dim3(8, Ng/64), 256, 0, stream>>>(nxt, fgW, fgb, fE, Ng, 480, Dd, 1);

    // pos branch -> [6400,32]
    pos_kernel<<<(Ng*32 + 255)/256, 256, 0, stream>>>(pos, bbgp, bbbp, bbmp, bbvp, fbW, fbb, pg);

    // mean over nodes -> hf[64,512]
    mean_kernel<<<(Bg*Dd + 255)/256, 256, 0, stream>>>(fE, pg, hf);

    // final BN + linear -> out[64,2]
    final_kernel<<<Bg, 256, 0, stream>>>(xb, hf, ftb, fng, fnb, fnm, fnv, fiW, fib, out);
}

// Round 2
// 979.613 us; speedup vs baseline: 2.6869x; 2.6869x over previous
//
#include <hip/hip_runtime.h>
#include <math.h>

#define Bg   64
#define Mg   100
#define Ng   6400
#define Eg   102400
#define Hh   4
#define Dd   512
#define HDd  2048
#define EMBd 768
#define IMGd 1024
#define EPSc 1e-5f

typedef unsigned short ushort_t;
typedef __bf16 bf16x8 __attribute__((ext_vector_type(8)));
typedef float  f32x4  __attribute__((ext_vector_type(4)));

__device__ __forceinline__ float eluf(float x) { return x > 0.f ? x : expm1f(x); }

__device__ __forceinline__ unsigned short f2bf(float x) {
    unsigned int u = __builtin_bit_cast(unsigned int, x);
    u += 0x7FFFu + ((u >> 16) & 1u);
    return (unsigned short)(u >> 16);
}
__device__ __forceinline__ float bf2f(unsigned short s) {
    return __builtin_bit_cast(float, ((unsigned int)s) << 16);
}

__device__ __forceinline__ void gld16(const void* g, void* l) {
    __builtin_amdgcn_global_load_lds(
        (const __attribute__((address_space(1))) void*)g,
        (__attribute__((address_space(3))) void*)l, 16, 0, 0);
}

// ---------------------------------------------------------------------------
// bf16 MFMA GEMM (m97 structure): C[M,N] = act(A[M,K] @ W[N,K]^T + bias)
// A, W bf16 row-major; acc fp32. 128x128 tile, BK=32, 256 thr (4 waves 2x2),
// each wave 64x64 = 4x4 MFMA 16x16x32 tiles. M%128==0, K%32==0; N guarded.
// act: 0=none 1=elu. outbf: 1 -> bf16 out, 0 -> f32 out.
// ---------------------------------------------------------------------------
__global__ __launch_bounds__(256)
void gemm_bf16(const unsigned short* __restrict__ A,
               const unsigned short* __restrict__ W,
               const float* __restrict__ bias, void* __restrict__ C,
               int M, int N, int K, int act, int outbf)
{
    __shared__ __align__(16) unsigned short As[128 * 32];
    __shared__ __align__(16) unsigned short Bs[128 * 32];
    const int tid  = threadIdx.x;
    const int lane = tid & 63, wid = tid >> 6;
    const int bm = blockIdx.y * 128, bn = blockIdx.x * 128;
    const int wm = (wid >> 1) * 64, wn = (wid & 1) * 64;
    const int lrow = lane >> 2;          // 0..15
    const int lcol = (lane & 3) << 3;    // 0,8,16,24

    f32x4 acc[4][4] = {};

    const int ra = wid * 32;             // this wave stages tile rows ra..ra+31
    const unsigned short* gA0 = A + (size_t)(bm + ra + lrow) * K + lcol;
    const unsigned short* gA1 = A + (size_t)(bm + ra + 16 + lrow) * K + lcol;
    int rb0 = bn + ra + lrow;       if (rb0 >= N) rb0 = N - 1;
    int rb1 = bn + ra + 16 + lrow;  if (rb1 >= N) rb1 = N - 1;
    const unsigned short* gB0 = W + (size_t)rb0 * K + lcol;
    const unsigned short* gB1 = W + (size_t)rb1 * K + lcol;
    unsigned short* lA0 = &As[(ra)      * 32];   // wave-uniform LDS bases
    unsigned short* lA1 = &As[(ra + 16) * 32];
    unsigned short* lB0 = &Bs[(ra)      * 32];
    unsigned short* lB1 = &Bs[(ra + 16) * 32];

    const int frow = lane & 15;          // fragment row within 16x16 tile
    const int quad = (lane >> 4) << 3;   // k-offset 0,8,16,24

    for (int k0 = 0; k0 < K; k0 += 32) {
        gld16(gA0 + k0, lA0);
        gld16(gA1 + k0, lA1);
        gld16(gB0 + k0, lB0);
        gld16(gB1 + k0, lB1);
        __syncthreads();
        bf16x8 af[4], bfr[4];
#pragma unroll
        for (int i = 0; i < 4; ++i)
            af[i]  = *(const bf16x8*)&As[(wm + i * 16 + frow) * 32 + quad];
#pragma unroll
        for (int i = 0; i < 4; ++i)
            bfr[i] = *(const bf16x8*)&Bs[(wn + i * 16 + frow) * 32 + quad];
#pragma unroll
        for (int mi = 0; mi < 4; ++mi)
#pragma unroll
            for (int ni = 0; ni < 4; ++ni)
                acc[mi][ni] = __builtin_amdgcn_mfma_f32_16x16x32_bf16(
                    af[mi], bfr[ni], acc[mi][ni], 0, 0, 0);
        __syncthreads();
    }

    const int crow0 = bm + wm + ((lane >> 4) << 2);
    const int ccol0 = bn + wn + (lane & 15);
#pragma unroll
    for (int mi = 0; mi < 4; ++mi) {
#pragma unroll
        for (int ni = 0; ni < 4; ++ni) {
            int col = ccol0 + ni * 16;
            if (col >= N) continue;
            float bv = bias ? bias[col] : 0.f;
#pragma unroll
            for (int r = 0; r < 4; ++r) {
                int row = crow0 + mi * 16 + r;
                float v = acc[mi][ni][r] + bv;
                if (act) v = eluf(v);
                if (outbf) ((unsigned short*)C)[(size_t)row * N + col] = f2bf(v);
                else       ((float*)C)[(size_t)row * N + col] = v;
            }
        }
    }
}

// ---------------------------------------------------------------------------
// fp32 GEMM for the tiny 64-row branches
// ---------------------------------------------------------------------------
__global__ __launch_bounds__(256)
void gemm_nt(const float* __restrict__ A, const float* __restrict__ W,
             const float* __restrict__ bias, float* __restrict__ C,
             int M, int N, int K, int act)
{
    __shared__ float As[16 * 68];
    __shared__ float Ws[16 * 68];
    const int tid = threadIdx.x;
    const int tx = tid & 15, ty = tid >> 4;
    const int bm = blockIdx.y * 64, bn = blockIdx.x * 64;
    const int lrow = tid >> 2;
    const int lk4  = (tid & 3) << 2;
    const int arow = bm + lrow;
    const int wrow = bn + lrow;
    const float* Aptr = A + (size_t)arow * K + lk4;
    const float* Wptr = W + (size_t)wrow * K + lk4;
    float acc[4][4] = {{0.f,0.f,0.f,0.f},{0.f,0.f,0.f,0.f},{0.f,0.f,0.f,0.f},{0.f,0.f,0.f,0.f}};

    for (int k0 = 0; k0 < K; k0 += 16) {
        float4 av = make_float4(0.f,0.f,0.f,0.f);
        float4 wv = make_float4(0.f,0.f,0.f,0.f);
        if (arow < M) av = *(const float4*)(Aptr + k0);
        if (wrow < N) wv = *(const float4*)(Wptr + k0);
        As[(lk4+0)*68 + lrow] = av.x;
        As[(lk4+1)*68 + lrow] = av.y;
        As[(lk4+2)*68 + lrow] = av.z;
        As[(lk4+3)*68 + lrow] = av.w;
        Ws[(lk4+0)*68 + lrow] = wv.x;
        Ws[(lk4+1)*68 + lrow] = wv.y;
        Ws[(lk4+2)*68 + lrow] = wv.z;
        Ws[(lk4+3)*68 + lrow] = wv.w;
        __syncthreads();
#pragma unroll
        for (int kk = 0; kk < 16; ++kk) {
            float4 a = *(const float4*)&As[kk*68 + (ty<<2)];
            float4 w = *(const float4*)&Ws[kk*68 + (tx<<2)];
            acc[0][0] += a.x*w.x; acc[0][1] += a.x*w.y; acc[0][2] += a.x*w.z; acc[0][3] += a.x*w.w;
            acc[1][0] += a.y*w.x; acc[1][1] += a.y*w.y; acc[1][2] += a.y*w.z; acc[1][3] += a.y*w.w;
            acc[2][0] += a.z*w.x; acc[2][1] += a.z*w.y; acc[2][2] += a.z*w.z; acc[2][3] += a.z*w.w;
            acc[3][0] += a.w*w.x; acc[3][1] += a.w*w.y; acc[3][2] += a.w*w.z; acc[3][3] += a.w*w.w;
        }
        __syncthreads();
    }

#pragma unroll
    for (int i = 0; i < 4; ++i) {
        int row = bm + (ty<<2) + i;
        int col = bn + (tx<<2);
        if (row < M && col < N) {
            float4 v;
            v.x = acc[i][0]; v.y = acc[i][1]; v.z = acc[i][2]; v.w = acc[i][3];
            if (bias) { v.x += bias[col]; v.y += bias[col+1]; v.z += bias[col+2]; v.w += bias[col+3]; }
            if (act == 1) { v.x = eluf(v.x); v.y = eluf(v.y); v.z = eluf(v.z); v.w = eluf(v.w); }
            *(float4*)(C + (size_t)row * N + col) = v;
        }
    }
}

// ---------------------------------------------------------------------------
__global__ void cvt_f2b(const float* __restrict__ x, unsigned short* __restrict__ y, int n)
{
    int i = blockIdx.x * 256 + threadIdx.x;
    if (i < n) y[i] = f2bf(x[i]);
}

__global__ void bn_col(const float* __restrict__ x, const float* __restrict__ g,
                       const float* __restrict__ b, const float* __restrict__ m,
                       const float* __restrict__ v, float* __restrict__ y,
                       int rows, int cols)
{
    int i = blockIdx.x * 256 + threadIdx.x;
    if (i >= rows * cols) return;
    int c = i % cols;
    float inv = rsqrtf(v[c] + EPSc);
    y[i] = (x[i] - m[c]) * inv * g[c] + b[c];
}

// BN over node-position p = n % 100 (channel dim), bf16 in/out
__global__ void bn_node_b(const unsigned short* __restrict__ x, const float* __restrict__ g,
                          const float* __restrict__ b, const float* __restrict__ m,
                          const float* __restrict__ v, unsigned short* __restrict__ y,
                          int total, int Cdim)
{
    int i = blockIdx.x * 256 + threadIdx.x;
    if (i >= total) return;
    int n = i / Cdim;
    int p = n % Mg;
    float inv = rsqrtf(v[p] + EPSc);
    y[i] = f2bf((bf2f(x[i]) - m[p]) * inv * g[p] + b[p]);
}

// ---------------------------------------------------------------------------
// CSR build by dst
// ---------------------------------------------------------------------------
__global__ void zero_i32(int* __restrict__ p, int n)
{
    int i = blockIdx.x * 256 + threadIdx.x;
    if (i < n) p[i] = 0;
}

__global__ void count_dst(const int* __restrict__ dst, int* __restrict__ counts, int E)
{
    int i = blockIdx.x * 256 + threadIdx.x;
    if (i < E) atomicAdd(&counts[dst[i]], 1);
}

__global__ __launch_bounds__(1024)
void scan_excl(const int* __restrict__ counts, int* __restrict__ offs,
               int* __restrict__ cursor, int n)
{
    __shared__ int sm[1024];
    __shared__ int carry;
    if (threadIdx.x == 0) carry = 0;
    __syncthreads();
    for (int base = 0; base < n; base += 1024) {
        int i = base + (int)threadIdx.x;
        int v = (i < n) ? counts[i] : 0;
        sm[threadIdx.x] = v;
        __syncthreads();
        for (int o = 1; o < 1024; o <<= 1) {
            int t = (threadIdx.x >= (unsigned)o) ? sm[threadIdx.x - o] : 0;
            __syncthreads();
            sm[threadIdx.x] += t;
            __syncthreads();
        }
        int incl = sm[threadIdx.x];
        int myc = carry;
        if (i < n) {
            int ex = myc + incl - v;
            offs[i] = ex;
            cursor[i] = ex;
        }
        __syncthreads();
        if (threadIdx.x == 1023) carry = myc + sm[1023];
        __syncthreads();
    }
    if (threadIdx.x == 0) offs[n] = carry;
}

__global__ void scatter_edges(const int* __restrict__ dst, int* __restrict__ cursor,
                              int* __restrict__ eid, int E)
{
    int i = blockIdx.x * 256 + threadIdx.x;
    if (i < E) {
        int p = atomicAdd(&cursor[dst[i]], 1);
        eid[p] = i;
    }
}

// ---------------------------------------------------------------------------
// el[n,h] = sum_d H[n, h*512+d] * al[h,d] ; er likewise. One wave per (n,h).
// Hm is bf16.
// ---------------------------------------------------------------------------
__global__ __launch_bounds__(256)
void elr_kernel(const unsigned short* __restrict__ Hm, const float* __restrict__ al,
                const float* __restrict__ ar, float* __restrict__ el,
                float* __restrict__ er)
{
    int wid = threadIdx.x >> 6, lane = threadIdx.x & 63;
    int g = (blockIdx.x << 2) + wid;          // (n,h) pair id
    int n = g >> 2, h = g & 3;
    const unsigned short* hp = Hm + ((size_t)n << 11) + (h << 9);
    const float* alp = al + (h << 9);
    const float* arp = ar + (h << 9);
    float se = 0.f, sr = 0.f;
    for (int d = lane; d < Dd; d += 64) {
        float x = bf2f(hp[d]);
        se += x * alp[d];
        sr += x * arp[d];
    }
#pragma unroll
    for (int o = 32; o > 0; o >>= 1) {
        se += __shfl_down(se, o, 64);
        sr += __shfl_down(sr, o, 64);
    }
    if (lane == 0) { el[g] = se; er[g] = sr; }
}

// ---------------------------------------------------------------------------
// GAT aggregation: one block per dst node, bf16 Hm in, bf16 out.
// ---------------------------------------------------------------------------
__global__ __launch_bounds__(256)
void gat_agg(const unsigned short* __restrict__ Hm, const float* __restrict__ el,
             const float* __restrict__ er, const int* __restrict__ src,
             const int* __restrict__ offs, const int* __restrict__ eid,
             const float* __restrict__ bias, unsigned short* __restrict__ out)
{
    int n = blockIdx.x;
    int tid = threadIdx.x;
    int beg = offs[n], end = offs[n + 1];
    int deg = end - beg;

    if (deg == 0) {
#pragma unroll
        for (int j = 0; j < 8; ++j) {
            int d = tid + (j << 8);
            out[((size_t)n << 11) + d] = f2bf(bias[d]);
        }
        return;
    }

    __shared__ float m_sh[4], s_sh[4], al_sh[4];
    __shared__ int   src_sh[128];
    __shared__ float logit_sh[512];
    __shared__ float w_sh[512];

    if (tid < 4) { m_sh[tid] = -INFINITY; s_sh[tid] = 0.f; }
    float acc[8] = {0.f,0.f,0.f,0.f,0.f,0.f,0.f,0.f};
    __syncthreads();

    for (int c0 = 0; c0 < deg; c0 += 128) {
        int cnt = min(128, deg - c0);
        for (int i = tid; i < cnt; i += 256) src_sh[i] = src[eid[beg + c0 + i]];
        __syncthreads();
        for (int idx = tid; idx < (cnt << 2); idx += 256) {
            int i = idx >> 2, h = idx & 3;
            float x = el[(src_sh[i] << 2) + h] + er[(n << 2) + h];
            logit_sh[idx] = x > 0.f ? x : 0.2f * x;
        }
        __syncthreads();
        if (tid < 4) {
            float cm = -INFINITY;
            for (int i = 0; i < cnt; ++i) cm = fmaxf(cm, logit_sh[(i << 2) + tid]);
            float mn = fmaxf(m_sh[tid], cm);
            al_sh[tid] = expf(m_sh[tid] - mn);
            m_sh[tid] = mn;
        }
        __syncthreads();
        for (int idx = tid; idx < (cnt << 2); idx += 256)
            w_sh[idx] = expf(logit_sh[idx] - m_sh[idx & 3]);
        __syncthreads();
        if (tid < 4) {
            float cs = 0.f;
            for (int i = 0; i < cnt; ++i) cs += w_sh[(i << 2) + tid];
            s_sh[tid] = s_sh[tid] * al_sh[tid] + cs;
        }
#pragma unroll
        for (int j = 0; j < 8; ++j) acc[j] *= al_sh[j >> 1];
        for (int i = 0; i < cnt; ++i) {
            const unsigned short* hp = Hm + ((size_t)src_sh[i] << 11);
#pragma unroll
            for (int j = 0; j < 8; ++j)
                acc[j] += w_sh[(i << 2) + (j >> 1)] * bf2f(hp[tid + (j << 8)]);
        }
        __syncthreads();
    }

#pragma unroll
    for (int j = 0; j < 8; ++j) {
        int d = tid + (j << 8);
        out[((size_t)n << 11) + d] = f2bf(acc[j] / s_sh[j >> 1] + bias[d]);
    }
}

// ---------------------------------------------------------------------------
__global__ void pos_kernel(const float* __restrict__ pos, const float* __restrict__ g,
                           const float* __restrict__ b, const float* __restrict__ m,
                           const float* __restrict__ v, const float* __restrict__ W,
                           const float* __restrict__ bias, float* __restrict__ out)
{
    int i = blockIdx.x * 256 + threadIdx.x;
    if (i >= Ng * 32) return;
    int n = i >> 5, o = i & 31;
    int p = n % Mg;
    float inv = rsqrtf(v[p] + EPSc);
    float sc = inv * g[p];
    float sh = b[p] - m[p] * sc;
    float acc = bias[o];
#pragma unroll
    for (int c = 0; c < 4; ++c) {
        float xv = pos[(n << 2) + c] * sc + sh;
        acc += xv * W[(o << 2) + c];
    }
    out[i] = eluf(acc);
}

__global__ void mean_kernel(const float* __restrict__ hg, const float* __restrict__ pg,
                            float* __restrict__ hf)
{
    int i = blockIdx.x * 256 + threadIdx.x;   // < 64*512
    int bb = i >> 9, c = i & 511;
    float s = 0.f;
    if (c < 480) {
        const float* p = hg + (size_t)bb * Mg * 480 + c;
        for (int mm = 0; mm < Mg; ++mm) s += p[mm * 480];
    } else {
        const float* p = pg + (size_t)bb * Mg * 32 + (c - 480);
        for (int mm = 0; mm < Mg; ++mm) s += p[mm * 32];
    }
    hf[i] = s * 0.01f;
}

__global__ __launch_bounds__(256)
void final_kernel(const float* __restrict__ x, const float* __restrict__ hf,
                  const float* __restrict__ ft, const float* __restrict__ g,
                  const float* __restrict__ b, const float* __restrict__ m,
                  const float* __restrict__ v, const float* __restrict__ W,
                  const float* __restrict__ bias, float* __restrict__ out)
{
    int bb = blockIdx.x;
    int tid = threadIdx.x;
    float a0 = 0.f, a1 = 0.f;
    for (int c = tid; c < 1536; c += 256) {
        float xv = (c < 512) ? x[bb * 512 + c]
                 : (c < 1024) ? hf[bb * 512 + (c - 512)]
                              : ft[bb * 512 + (c - 1024)];
        float z = (xv - m[c]) * rsqrtf(v[c] + EPSc) * g[c] + b[c];
        a0 += z * W[c];
        a1 += z * W[1536 + c];
    }
    __shared__ float r0[256], r1[256];
    r0[tid] = a0; r1[tid] = a1;
    __syncthreads();
    for (int o = 128; o > 0; o >>= 1) {
        if (tid < o) { r0[tid] += r0[tid + o]; r1[tid] += r1[tid + o]; }
        __syncthreads();
    }
    if (tid == 0) {
        out[bb * 2 + 0] = r0[0] + bias[0];
        out[bb * 2 + 1] = r1[0] + bias[1];
    }
}

// ---------------------------------------------------------------------------
extern "C" void kernel_launch(void* const* d_in, const int* in_sizes, int n_in,
                              void* d_out, int out_size, void* d_ws, size_t ws_size,
                              hipStream_t stream)
{
    (void)in_sizes; (void)n_in; (void)out_size; (void)ws_size;

    const float* img   = (const float*)d_in[0];
    const float* ftxt  = (const float*)d_in[1];
    const float* unixe = (const float*)d_in[2];
    const float* pos   = (const float*)d_in[3];
    const int*   src   = (const int*)  d_in[4];
    const int*   dst   = (const int*)  d_in[5];
    const float* g1W   = (const float*)d_in[6];
    const float* g1al  = (const float*)d_in[7];
    const float* g1ar  = (const float*)d_in[8];
    const float* g1b   = (const float*)d_in[9];
    const float* g2W   = (const float*)d_in[10];
    const float* g2al  = (const float*)d_in[11];
    const float* g2ar  = (const float*)d_in[12];
    const float* g2b   = (const float*)d_in[13];
    const float* fcW   = (const float*)d_in[14];
    const float* fcb   = (const float*)d_in[15];
    const float* hidW  = (const float*)d_in[16];
    const float* hidb  = (const float*)d_in[17];
    const float* btg   = (const float*)d_in[18];
    const float* btb   = (const float*)d_in[19];
    const float* btm   = (const float*)d_in[20];
    const float* btv   = (const float*)d_in[21];
    const float* ftW   = (const float*)d_in[22];
    const float* ftbi  = (const float*)d_in[23];
    const float* swg   = (const float*)d_in[24];
    const float* swb   = (const float*)d_in[25];
    const float* swm   = (const float*)d_in[26];
    const float* swv   = (const float*)d_in[27];
    const float* swW   = (const float*)d_in[28];
    const float* swbi  = (const float*)d_in[29];
    const float* bgg   = (const float*)d_in[30];
    const float* bgb   = (const float*)d_in[31];
    const float* bgm   = (const float*)d_in[32];
    const float* bgv   = (const float*)d_in[33];
    const float* fgW   = (const float*)d_in[34];
    const float* fgb   = (const float*)d_in[35];
    const float* bbgp  = (const float*)d_in[36];
    const float* bbbp  = (const float*)d_in[37];
    const float* bbmp  = (const float*)d_in[38];
    const float* bbvp  = (const float*)d_in[39];
    const float* fbW   = (const float*)d_in[40];
    const float* fbb   = (const float*)d_in[41];
    const float* fng   = (const float*)d_in[42];
    const float* fnb   = (const float*)d_in[43];
    const float* fnm   = (const float*)d_in[44];
    const float* fnv   = (const float*)d_in[45];
    const float* fiW   = (const float*)d_in[46];
    const float* fib   = (const float*)d_in[47];
    float* out = (float*)d_out;

    // ---- workspace layout (all chunks 16B aligned) ----
    char* p = (char*)d_ws;
    unsigned short* fA  = (unsigned short*)p; p += (size_t)Ng * HDd * 2;   // bf16 [6400,2048]
    unsigned short* fB  = (unsigned short*)p; p += (size_t)Ng * HDd * 2;   // bf16 [6400,2048]
    unsigned short* fC  = (unsigned short*)p; p += (size_t)Ng * Dd * 2;    // bf16 [6400,512]
    unsigned short* fD  = (unsigned short*)p; p += (size_t)Ng * Dd * 2;    // bf16 [6400,512]
    float*          fE  = (float*)p;          p += (size_t)Ng * 480 * 4;   // f32  [6400,480]
    float*          pg  = (float*)p;          p += (size_t)Ng * 32 * 4;    // f32  [6400,32]
    float*          el  = (float*)p;          p += (size_t)Ng * Hh * 4;
    float*          er  = (float*)p;          p += (size_t)Ng * Hh * 4;
    float*          xb  = (float*)p;          p += (size_t)Bg * Dd * 4;
    float*          ftb = (float*)p;          p += (size_t)Bg * Dd * 4;
    float*          hf  = (float*)p;          p += (size_t)Bg * Dd * 4;
    float*          ti  = (float*)p;          p += (size_t)Bg * IMGd * 4;
    float*          tt  = (float*)p;          p += (size_t)Bg * EMBd * 4;
    unsigned short* ubf = (unsigned short*)p; p += (size_t)Ng * EMBd * 2;  // unix bf16
    unsigned short* wg1 = (unsigned short*)p; p += (size_t)HDd * EMBd * 2;
    unsigned short* wg2 = (unsigned short*)p; p += (size_t)HDd * HDd * 2;
    unsigned short* wfc = (unsigned short*)p; p += (size_t)Dd * HDd * 2;
    unsigned short* whid= (unsigned short*)p; p += (size_t)8 * Dd * Dd * 2;
    unsigned short* wfg = (unsigned short*)p; p += (size_t)480 * Dd * 2;
    int* counts = (int*)p; p += (size_t)Ng * 4;
    int* offs   = (int*)p; p += (size_t)(Ng + 1) * 4 + 12;  // keep alignment
    int* cursor = (int*)p; p += (size_t)Ng * 4;
    int* eid    = (int*)p; p += (size_t)Eg * 4;

    // ---- weight / input conversions to bf16 ----
    cvt_f2b<<<(Ng*EMBd + 255)/256, 256, 0, stream>>>(unixe, ubf, Ng*EMBd);
    cvt_f2b<<<(HDd*EMBd + 255)/256, 256, 0, stream>>>(g1W, wg1, HDd*EMBd);
    cvt_f2b<<<(HDd*HDd + 255)/256, 256, 0, stream>>>(g2W, wg2, HDd*HDd);
    cvt_f2b<<<(Dd*HDd + 255)/256, 256, 0, stream>>>(fcW, wfc, Dd*HDd);
    cvt_f2b<<<(8*Dd*Dd + 255)/256, 256, 0, stream>>>(hidW, whid, 8*Dd*Dd);
    cvt_f2b<<<(480*Dd + 255)/256, 256, 0, stream>>>(fgW, wfg, 480*Dd);

    // ---- image / text branches (fp32, tiny) ----
    bn_col<<<(Bg*IMGd + 255)/256, 256, 0, stream>>>(img, swg, swb, swm, swv, ti, Bg, IMGd);
    gemm_nt<<<dim3(8, 1), 256, 0, stream>>>(ti, swW, swbi, xb, Bg, Dd, IMGd, 1);
    bn_col<<<(Bg*EMBd + 255)/256, 256, 0, stream>>>(ftxt, btg, btb, btm, btv, tt, Bg, EMBd);
    gemm_nt<<<dim3(8, 1), 256, 0, stream>>>(tt, ftW, ftbi, ftb, Bg, Dd, EMBd, 1);

    // ---- CSR by dst ----
    zero_i32<<<(Ng + 255)/256, 256, 0, stream>>>(counts, Ng);
    count_dst<<<(Eg + 255)/256, 256, 0, stream>>>(dst, counts, Eg);
    scan_excl<<<1, 1024, 0, stream>>>(counts, offs, cursor, Ng);
    scatter_edges<<<(Eg + 255)/256, 256, 0, stream>>>(dst, cursor, eid, Eg);

    // ---- GAT layer 1: h = unix @ W1^T ----
    gemm_bf16<<<dim3(HDd/128, Ng/128), 256, 0, stream>>>(ubf, wg1, nullptr, fA, Ng, HDd, EMBd, 0, 1);
    elr_kernel<<<Ng, 256, 0, stream>>>(fA, g1al, g1ar, el, er);
    gat_agg<<<Ng, 256, 0, stream>>>(fA, el, er, src, offs, eid, g1b, fB);

    // ---- GAT layer 2 ----
    gemm_bf16<<<dim3(HDd/128, Ng/128), 256, 0, stream>>>(fB, wg2, nullptr, fA, Ng, HDd, HDd, 0, 1);
    elr_kernel<<<Ng, 256, 0, stream>>>(fA, g2al, g2ar, el, er);
    gat_agg<<<Ng, 256, 0, stream>>>(fA, el, er, src, offs, eid, g2b, fB);

    // ---- fc: [6400,2048] -> [6400,512], elu, bf16 out ----
    gemm_bf16<<<dim3(Dd/128, Ng/128), 256, 0, stream>>>(fB, wfc, fcb, fC, Ng, Dd, HDd, 1, 1);

    // ---- 8 hidden layers, ping-pong fC<->fD (bf16) ----
    unsigned short* cur = fC; unsigned short* nxt = fD;
    for (int i = 0; i < 8; ++i) {
        gemm_bf16<<<dim3(Dd/128, Ng/128), 256, 0, stream>>>(
            cur, whid + (size_t)i * Dd * Dd, hidb + (size_t)i * Dd, nxt, Ng, Dd, Dd, 1, 1);
        unsigned short* t = cur; cur = nxt; nxt = t;
    }
    // result in fC (cur == fC after 8 swaps)

    // ---- BN over node position (bf16 in/out), then fc_gat -> [6400,480] f32 ----
    bn_node_b<<<(Ng*Dd + 255)/256, 256, 0, stream>>>(cur, bgg, bgb, bgm, bgv, nxt, Ng*Dd, Dd);
    gemm_bf16<<<dim3(4, Ng/128), 256, 0, stream>>>(nxt, wfg, fgb, fE, Ng, 480, Dd, 1, 0);

    // ---- pos branch -> [6400,32] ----
    pos_kernel<<<(Ng*32 + 255)/256, 256, 0, stream>>>(pos, bbgp, bbbp, bbmp, bbvp, fbW, fbb, pg);

    // ---- mean over nodes -> hf[64,512] ----
    mean_kernel<<<(Bg*Dd + 255)/256, 256, 0, stream>>>(fE, pg, hf);

    // ---- final BN + linear -> out[64,2] ----
    final_kernel<<<Bg, 256, 0, stream>>>(xb, hf, ftb, fng, fnb, fnm, fnv, fiW, fib, out);
}

// Round 3
// 850.290 us; speedup vs baseline: 3.0955x; 1.1521x over previous
//
#include <hip/hip_runtime.h>
#include <math.h>

#define Bg   64
#define Mg   100
#define Ng   6400
#define Eg   102400
#define Hh   4
#define Dd   512
#define HDd  2048
#define EMBd 768
#define IMGd 1024
#define EPSc 1e-5f

typedef __bf16 bf16x8 __attribute__((ext_vector_type(8)));
typedef float  f32x4  __attribute__((ext_vector_type(4)));

__device__ __forceinline__ float eluf(float x) { return x > 0.f ? x : expm1f(x); }

__device__ __forceinline__ unsigned short f2bf(float x) {
    unsigned int u = __builtin_bit_cast(unsigned int, x);
    u += 0x7FFFu + ((u >> 16) & 1u);
    return (unsigned short)(u >> 16);
}
__device__ __forceinline__ float bf2f(unsigned short s) {
    return __builtin_bit_cast(float, ((unsigned int)s) << 16);
}

__device__ __forceinline__ void gld16(const void* g, void* l) {
    __builtin_amdgcn_global_load_lds(
        (const __attribute__((address_space(1))) void*)g,
        (__attribute__((address_space(3))) void*)l, 16, 0, 0);
}

// ---------------------------------------------------------------------------
// bf16 MFMA GEMM, 128x128 tile (m97 structure): C = act(A[M,K] @ W[N,K]^T + b)
// ---------------------------------------------------------------------------
__global__ __launch_bounds__(256)
void gemm_bf16(const unsigned short* __restrict__ A,
               const unsigned short* __restrict__ W,
               const float* __restrict__ bias, void* __restrict__ C,
               int M, int N, int K, int act, int outbf)
{
    __shared__ __align__(16) unsigned short As[128 * 32];
    __shared__ __align__(16) unsigned short Bs[128 * 32];
    const int tid  = threadIdx.x;
    const int lane = tid & 63, wid = tid >> 6;
    const int bm = blockIdx.y * 128, bn = blockIdx.x * 128;
    const int wm = (wid >> 1) * 64, wn = (wid & 1) * 64;
    const int lrow = lane >> 2;
    const int lcol = (lane & 3) << 3;

    f32x4 acc[4][4] = {};

    const int ra = wid * 32;
    const unsigned short* gA0 = A + (size_t)(bm + ra + lrow) * K + lcol;
    const unsigned short* gA1 = A + (size_t)(bm + ra + 16 + lrow) * K + lcol;
    int rb0 = bn + ra + lrow;       if (rb0 >= N) rb0 = N - 1;
    int rb1 = bn + ra + 16 + lrow;  if (rb1 >= N) rb1 = N - 1;
    const unsigned short* gB0 = W + (size_t)rb0 * K + lcol;
    const unsigned short* gB1 = W + (size_t)rb1 * K + lcol;
    unsigned short* lA0 = &As[(ra)      * 32];
    unsigned short* lA1 = &As[(ra + 16) * 32];
    unsigned short* lB0 = &Bs[(ra)      * 32];
    unsigned short* lB1 = &Bs[(ra + 16) * 32];

    const int frow = lane & 15;
    const int quad = (lane >> 4) << 3;

    for (int k0 = 0; k0 < K; k0 += 32) {
        gld16(gA0 + k0, lA0);
        gld16(gA1 + k0, lA1);
        gld16(gB0 + k0, lB0);
        gld16(gB1 + k0, lB1);
        __syncthreads();
        bf16x8 af[4], bfr[4];
#pragma unroll
        for (int i = 0; i < 4; ++i)
            af[i]  = *(const bf16x8*)&As[(wm + i * 16 + frow) * 32 + quad];
#pragma unroll
        for (int i = 0; i < 4; ++i)
            bfr[i] = *(const bf16x8*)&Bs[(wn + i * 16 + frow) * 32 + quad];
#pragma unroll
        for (int mi = 0; mi < 4; ++mi)
#pragma unroll
            for (int ni = 0; ni < 4; ++ni)
                acc[mi][ni] = __builtin_amdgcn_mfma_f32_16x16x32_bf16(
                    af[mi], bfr[ni], acc[mi][ni], 0, 0, 0);
        __syncthreads();
    }

    const int crow0 = bm + wm + ((lane >> 4) << 2);
    const int ccol0 = bn + wn + (lane & 15);
#pragma unroll
    for (int mi = 0; mi < 4; ++mi) {
#pragma unroll
        for (int ni = 0; ni < 4; ++ni) {
            int col = ccol0 + ni * 16;
            if (col >= N) continue;
            float bv = bias ? bias[col] : 0.f;
#pragma unroll
            for (int r = 0; r < 4; ++r) {
                int row = crow0 + mi * 16 + r;
                float v = acc[mi][ni][r] + bv;
                if (act) v = eluf(v);
                if (outbf) ((unsigned short*)C)[(size_t)row * N + col] = f2bf(v);
                else       ((float*)C)[(size_t)row * N + col] = v;
            }
        }
    }
}

// ---------------------------------------------------------------------------
// bf16 MFMA GEMM, 64x64 tile: for narrow-N layers (fc, hidden, fc_gat).
// 4 waves in 2x2, wave tile 32x32 (2x2 MFMA). Grid (N/64)x(M/64) -> 800
// blocks for N=512, vs 200 with 128-tiles: occupancy fix.
// ---------------------------------------------------------------------------
__global__ __launch_bounds__(256)
void gemm_bf16_t64(const unsigned short* __restrict__ A,
                   const unsigned short* __restrict__ W,
                   const float* __restrict__ bias, void* __restrict__ C,
                   int M, int N, int K, int act, int outbf)
{
    __shared__ __align__(16) unsigned short As[64 * 32];
    __shared__ __align__(16) unsigned short Bs[64 * 32];
    const int tid  = threadIdx.x;
    const int lane = tid & 63, wid = tid >> 6;
    const int bm = blockIdx.y * 64, bn = blockIdx.x * 64;
    const int wm = (wid >> 1) * 32, wn = (wid & 1) * 32;
    const int lrow = lane >> 2;
    const int lcol = (lane & 3) << 3;

    f32x4 acc[2][2] = {};

    const int ra = wid * 16;
    const unsigned short* gA = A + (size_t)(bm + ra + lrow) * K + lcol;
    int rb = bn + ra + lrow; if (rb >= N) rb = N - 1;
    const unsigned short* gB = W + (size_t)rb * K + lcol;
    unsigned short* lA = &As[ra * 32];
    unsigned short* lB = &Bs[ra * 32];

    const int frow = lane & 15;
    const int quad = (lane >> 4) << 3;

    for (int k0 = 0; k0 < K; k0 += 32) {
        gld16(gA + k0, lA);
        gld16(gB + k0, lB);
        __syncthreads();
        bf16x8 af0 = *(const bf16x8*)&As[(wm + frow) * 32 + quad];
        bf16x8 af1 = *(const bf16x8*)&As[(wm + 16 + frow) * 32 + quad];
        bf16x8 bf0 = *(const bf16x8*)&Bs[(wn + frow) * 32 + quad];
        bf16x8 bf1 = *(const bf16x8*)&Bs[(wn + 16 + frow) * 32 + quad];
        acc[0][0] = __builtin_amdgcn_mfma_f32_16x16x32_bf16(af0, bf0, acc[0][0], 0, 0, 0);
        acc[0][1] = __builtin_amdgcn_mfma_f32_16x16x32_bf16(af0, bf1, acc[0][1], 0, 0, 0);
        acc[1][0] = __builtin_amdgcn_mfma_f32_16x16x32_bf16(af1, bf0, acc[1][0], 0, 0, 0);
        acc[1][1] = __builtin_amdgcn_mfma_f32_16x16x32_bf16(af1, bf1, acc[1][1], 0, 0, 0);
        __syncthreads();
    }

    const int crow0 = bm + wm + ((lane >> 4) << 2);
    const int ccol0 = bn + wn + (lane & 15);
#pragma unroll
    for (int mi = 0; mi < 2; ++mi) {
#pragma unroll
        for (int ni = 0; ni < 2; ++ni) {
            int col = ccol0 + ni * 16;
            if (col >= N) continue;
            float bv = bias ? bias[col] : 0.f;
#pragma unroll
            for (int r = 0; r < 4; ++r) {
                int row = crow0 + mi * 16 + r;
                float v = acc[mi][ni][r] + bv;
                if (act) v = eluf(v);
                if (outbf) ((unsigned short*)C)[(size_t)row * N + col] = f2bf(v);
                else       ((float*)C)[(size_t)row * N + col] = v;
            }
        }
    }
}

// ---------------------------------------------------------------------------
// fp32 GEMM for the tiny 64-row branches
// ---------------------------------------------------------------------------
__global__ __launch_bounds__(256)
void gemm_nt(const float* __restrict__ A, const float* __restrict__ W,
             const float* __restrict__ bias, float* __restrict__ C,
             int M, int N, int K, int act)
{
    __shared__ float As[16 * 68];
    __shared__ float Ws[16 * 68];
    const int tid = threadIdx.x;
    const int tx = tid & 15, ty = tid >> 4;
    const int bm = blockIdx.y * 64, bn = blockIdx.x * 64;
    const int lrow = tid >> 2;
    const int lk4  = (tid & 3) << 2;
    const int arow = bm + lrow;
    const int wrow = bn + lrow;
    const float* Aptr = A + (size_t)arow * K + lk4;
    const float* Wptr = W + (size_t)wrow * K + lk4;
    float acc[4][4] = {{0.f,0.f,0.f,0.f},{0.f,0.f,0.f,0.f},{0.f,0.f,0.f,0.f},{0.f,0.f,0.f,0.f}};

    for (int k0 = 0; k0 < K; k0 += 16) {
        float4 av = make_float4(0.f,0.f,0.f,0.f);
        float4 wv = make_float4(0.f,0.f,0.f,0.f);
        if (arow < M) av = *(const float4*)(Aptr + k0);
        if (wrow < N) wv = *(const float4*)(Wptr + k0);
        As[(lk4+0)*68 + lrow] = av.x;
        As[(lk4+1)*68 + lrow] = av.y;
        As[(lk4+2)*68 + lrow] = av.z;
        As[(lk4+3)*68 + lrow] = av.w;
        Ws[(lk4+0)*68 + lrow] = wv.x;
        Ws[(lk4+1)*68 + lrow] = wv.y;
        Ws[(lk4+2)*68 + lrow] = wv.z;
        Ws[(lk4+3)*68 + lrow] = wv.w;
        __syncthreads();
#pragma unroll
        for (int kk = 0; kk < 16; ++kk) {
            float4 a = *(const float4*)&As[kk*68 + (ty<<2)];
            float4 w = *(const float4*)&Ws[kk*68 + (tx<<2)];
            acc[0][0] += a.x*w.x; acc[0][1] += a.x*w.y; acc[0][2] += a.x*w.z; acc[0][3] += a.x*w.w;
            acc[1][0] += a.y*w.x; acc[1][1] += a.y*w.y; acc[1][2] += a.y*w.z; acc[1][3] += a.y*w.w;
            acc[2][0] += a.z*w.x; acc[2][1] += a.z*w.y; acc[2][2] += a.z*w.z; acc[2][3] += a.z*w.w;
            acc[3][0] += a.w*w.x; acc[3][1] += a.w*w.y; acc[3][2] += a.w*w.z; acc[3][3] += a.w*w.w;
        }
        __syncthreads();
    }

#pragma unroll
    for (int i = 0; i < 4; ++i) {
        int row = bm + (ty<<2) + i;
        int col = bn + (tx<<2);
        if (row < M && col < N) {
            float4 v;
            v.x = acc[i][0]; v.y = acc[i][1]; v.z = acc[i][2]; v.w = acc[i][3];
            if (bias) { v.x += bias[col]; v.y += bias[col+1]; v.z += bias[col+2]; v.w += bias[col+3]; }
            if (act == 1) { v.x = eluf(v.x); v.y = eluf(v.y); v.z = eluf(v.z); v.w = eluf(v.w); }
            *(float4*)(C + (size_t)row * N + col) = v;
        }
    }
}

// ---------------------------------------------------------------------------
// Merged fp32 -> bf16 conversion for 6 arrays (4-wide; all sizes %4 == 0).
// ---------------------------------------------------------------------------
struct CvtPack {
    const float* s[6];
    unsigned short* d[6];
    int n4[6];
};

__global__ void cvt_all(CvtPack p, int total4)
{
    int i = blockIdx.x * 256 + threadIdx.x;
    if (i >= total4) return;
#pragma unroll
    for (int k = 0; k < 6; ++k) {
        if (i < p.n4[k]) {
            float4 v = ((const float4*)p.s[k])[i];
            ushort4 o;
            o.x = f2bf(v.x); o.y = f2bf(v.y); o.z = f2bf(v.z); o.w = f2bf(v.w);
            ((ushort4*)p.d[k])[i] = o;
            return;
        }
        i -= p.n4[k];
    }
}

// ---------------------------------------------------------------------------
__global__ void bn_col(const float* __restrict__ x, const float* __restrict__ g,
                       const float* __restrict__ b, const float* __restrict__ m,
                       const float* __restrict__ v, float* __restrict__ y,
                       int rows, int cols)
{
    int i = blockIdx.x * 256 + threadIdx.x;
    if (i >= rows * cols) return;
    int c = i % cols;
    float inv = rsqrtf(v[c] + EPSc);
    y[i] = (x[i] - m[c]) * inv * g[c] + b[c];
}

// BN over node-position p = n % 100, bf16 in/out, 4-wide (Cdim4 = Cdim/4)
__global__ void bn_node_b4(const ushort4* __restrict__ x, const float* __restrict__ g,
                           const float* __restrict__ b, const float* __restrict__ m,
                           const float* __restrict__ v, ushort4* __restrict__ y,
                           int total4, int Cdim4)
{
    int i = blockIdx.x * 256 + threadIdx.x;
    if (i >= total4) return;
    int n = i / Cdim4;
    int p = n % Mg;
    float sc = rsqrtf(v[p] + EPSc) * g[p];
    float sh = b[p] - m[p] * sc;
    ushort4 xv = x[i];
    ushort4 o;
    o.x = f2bf(bf2f(xv.x) * sc + sh);
    o.y = f2bf(bf2f(xv.y) * sc + sh);
    o.z = f2bf(bf2f(xv.z) * sc + sh);
    o.w = f2bf(bf2f(xv.w) * sc + sh);
    y[i] = o;
}

// ---------------------------------------------------------------------------
// CSR build by dst
// ---------------------------------------------------------------------------
__global__ void zero_i32(int* __restrict__ p, int n)
{
    int i = blockIdx.x * 256 + threadIdx.x;
    if (i < n) p[i] = 0;
}

__global__ void count_dst(const int* __restrict__ dst, int* __restrict__ counts, int E)
{
    int i = blockIdx.x * 256 + threadIdx.x;
    if (i < E) atomicAdd(&counts[dst[i]], 1);
}

__global__ __launch_bounds__(1024)
void scan_excl(const int* __restrict__ counts, int* __restrict__ offs,
               int* __restrict__ cursor, int n)
{
    __shared__ int sm[1024];
    __shared__ int carry;
    if (threadIdx.x == 0) carry = 0;
    __syncthreads();
    for (int base = 0; base < n; base += 1024) {
        int i = base + (int)threadIdx.x;
        int v = (i < n) ? counts[i] : 0;
        sm[threadIdx.x] = v;
        __syncthreads();
        for (int o = 1; o < 1024; o <<= 1) {
            int t = (threadIdx.x >= (unsigned)o) ? sm[threadIdx.x - o] : 0;
            __syncthreads();
            sm[threadIdx.x] += t;
            __syncthreads();
        }
        int incl = sm[threadIdx.x];
        int myc = carry;
        if (i < n) {
            int ex = myc + incl - v;
            offs[i] = ex;
            cursor[i] = ex;
        }
        __syncthreads();
        if (threadIdx.x == 1023) carry = myc + sm[1023];
        __syncthreads();
    }
    if (threadIdx.x == 0) offs[n] = carry;
}

__global__ void scatter_edges(const int* __restrict__ dst, int* __restrict__ cursor,
                              int* __restrict__ eid, int E)
{
    int i = blockIdx.x * 256 + threadIdx.x;
    if (i < E) {
        int p = atomicAdd(&cursor[dst[i]], 1);
        eid[p] = i;
    }
}

// ---------------------------------------------------------------------------
// el/er: one wave per (n,h); lane owns 8 consecutive dims -> one 16B load.
// ---------------------------------------------------------------------------
__global__ __launch_bounds__(256)
void elr_kernel(const unsigned short* __restrict__ Hm, const float* __restrict__ al,
                const float* __restrict__ ar, float* __restrict__ el,
                float* __restrict__ er)
{
    int wid = threadIdx.x >> 6, lane = threadIdx.x & 63;
    int g = (blockIdx.x << 2) + wid;
    int n = g >> 2, h = g & 3;
    const unsigned short* hp = Hm + ((size_t)n << 11) + (h << 9) + (lane << 3);
    const float* alp = al + (h << 9) + (lane << 3);
    const float* arp = ar + (h << 9) + (lane << 3);
    ushort4 x0 = *(const ushort4*)hp;
    ushort4 x1 = *(const ushort4*)(hp + 4);
    float4 l0 = *(const float4*)alp, l1 = *(const float4*)(alp + 4);
    float4 r0 = *(const float4*)arp, r1 = *(const float4*)(arp + 4);
    float a0 = bf2f(x0.x), a1 = bf2f(x0.y), a2 = bf2f(x0.z), a3 = bf2f(x0.w);
    float a4 = bf2f(x1.x), a5 = bf2f(x1.y), a6 = bf2f(x1.z), a7 = bf2f(x1.w);
    float se = a0*l0.x + a1*l0.y + a2*l0.z + a3*l0.w + a4*l1.x + a5*l1.y + a6*l1.z + a7*l1.w;
    float sr = a0*r0.x + a1*r0.y + a2*r0.z + a3*r0.w + a4*r1.x + a5*r1.y + a6*r1.z + a7*r1.w;
#pragma unroll
    for (int o = 32; o > 0; o >>= 1) {
        se += __shfl_down(se, o, 64);
        sr += __shfl_down(sr, o, 64);
    }
    if (lane == 0) { el[g] = se; er[g] = sr; }
}

// ---------------------------------------------------------------------------
// GAT aggregation: one block per dst node. Thread owns dims [4t,4t+4) and
// [1024+4t, 1024+4t+4) -> two 8B loads per edge, 2 heads per thread.
// ---------------------------------------------------------------------------
__global__ __launch_bounds__(256)
void gat_agg(const unsigned short* __restrict__ Hm, const float* __restrict__ el,
             const float* __restrict__ er, const int* __restrict__ src,
             const int* __restrict__ offs, const int* __restrict__ eid,
             const float* __restrict__ bias, unsigned short* __restrict__ out)
{
    int n = blockIdx.x;
    int tid = threadIdx.x;
    int beg = offs[n], end = offs[n + 1];
    int deg = end - beg;
    const int b0 = tid << 2;          // dims 0..1023
    const int b1 = 1024 + (tid << 2); // dims 1024..2047
    const int h0 = tid >> 7;          // head of b0 (0 or 1)
    const int h1 = h0 + 2;            // head of b1

    if (deg == 0) {
#pragma unroll
        for (int j = 0; j < 4; ++j) {
            out[((size_t)n << 11) + b0 + j] = f2bf(bias[b0 + j]);
            out[((size_t)n << 11) + b1 + j] = f2bf(bias[b1 + j]);
        }
        return;
    }

    __shared__ float m_sh[4], s_sh[4], al_sh[4];
    __shared__ int   src_sh[128];
    __shared__ float logit_sh[512];
    __shared__ float w_sh[512];

    if (tid < 4) { m_sh[tid] = -INFINITY; s_sh[tid] = 0.f; }
    float acc[8] = {0.f,0.f,0.f,0.f,0.f,0.f,0.f,0.f};
    __syncthreads();

    for (int c0 = 0; c0 < deg; c0 += 128) {
        int cnt = min(128, deg - c0);
        for (int i = tid; i < cnt; i += 256) src_sh[i] = src[eid[beg + c0 + i]];
        __syncthreads();
        for (int idx = tid; idx < (cnt << 2); idx += 256) {
            int i = idx >> 2, h = idx & 3;
            float x = el[(src_sh[i] << 2) + h] + er[(n << 2) + h];
            logit_sh[idx] = x > 0.f ? x : 0.2f * x;
        }
        __syncthreads();
        if (tid < 4) {
            float cm = -INFINITY;
            for (int i = 0; i < cnt; ++i) cm = fmaxf(cm, logit_sh[(i << 2) + tid]);
            float mn = fmaxf(m_sh[tid], cm);
            al_sh[tid] = expf(m_sh[tid] - mn);
            m_sh[tid] = mn;
        }
        __syncthreads();
        for (int idx = tid; idx < (cnt << 2); idx += 256)
            w_sh[idx] = expf(logit_sh[idx] - m_sh[idx & 3]);
        __syncthreads();
        if (tid < 4) {
            float cs = 0.f;
            for (int i = 0; i < cnt; ++i) cs += w_sh[(i << 2) + tid];
            s_sh[tid] = s_sh[tid] * al_sh[tid] + cs;
        }
        float r0 = al_sh[h0], r1 = al_sh[h1];
        acc[0] *= r0; acc[1] *= r0; acc[2] *= r0; acc[3] *= r0;
        acc[4] *= r1; acc[5] *= r1; acc[6] *= r1; acc[7] *= r1;
        for (int i = 0; i < cnt; ++i) {
            const unsigned short* hp = Hm + ((size_t)src_sh[i] << 11);
            ushort4 a = *(const ushort4*)(hp + b0);
            ushort4 b = *(const ushort4*)(hp + b1);
            float w0 = w_sh[(i << 2) + h0], w1 = w_sh[(i << 2) + h1];
            acc[0] += w0 * bf2f(a.x); acc[1] += w0 * bf2f(a.y);
            acc[2] += w0 * bf2f(a.z); acc[3] += w0 * bf2f(a.w);
            acc[4] += w1 * bf2f(b.x); acc[5] += w1 * bf2f(b.y);
            acc[6] += w1 * bf2f(b.z); acc[7] += w1 * bf2f(b.w);
        }
        __syncthreads();
    }

    float is0 = 1.f / s_sh[h0], is1 = 1.f / s_sh[h1];
#pragma unroll
    for (int j = 0; j < 4; ++j) {
        out[((size_t)n << 11) + b0 + j] = f2bf(acc[j] * is0 + bias[b0 + j]);
        out[((size_t)n << 11) + b1 + j] = f2bf(acc[4 + j] * is1 + bias[b1 + j]);
    }
}

// ---------------------------------------------------------------------------
// mean over 100 nodes of concat([hg 480, pos-branch 32]) -> hf[64,512].
// pos branch computed inline (p = n%100 = m within a graph).
// ---------------------------------------------------------------------------
__global__ void mean_kernel(const float* __restrict__ hg, const float* __restrict__ pos,
                            const float* __restrict__ bg, const float* __restrict__ bb_,
                            const float* __restrict__ bm_, const float* __restrict__ bv_,
                            const float* __restrict__ W, const float* __restrict__ bias,
                            float* __restrict__ hf)
{
    int i = blockIdx.x * 256 + threadIdx.x;   // < 64*512
    if (i >= Bg * Dd) return;
    int bb = i >> 9, c = i & 511;
    float s = 0.f;
    if (c < 480) {
        const float* p = hg + (size_t)bb * Mg * 480 + c;
        for (int mm = 0; mm < Mg; ++mm) s += p[mm * 480];
    } else {
        int o = c - 480;
        float w0 = W[(o << 2) + 0], w1 = W[(o << 2) + 1];
        float w2 = W[(o << 2) + 2], w3 = W[(o << 2) + 3];
        float bo = bias[o];
        const float* pp = pos + (size_t)bb * Mg * 4;
        for (int mm = 0; mm < Mg; ++mm) {
            float sc = rsqrtf(bv_[mm] + EPSc) * bg[mm];
            float sh = bb_[mm] - bm_[mm] * sc;
            float a = bo + (pp[mm*4+0]*sc+sh)*w0 + (pp[mm*4+1]*sc+sh)*w1
                         + (pp[mm*4+2]*sc+sh)*w2 + (pp[mm*4+3]*sc+sh)*w3;
            s += eluf(a);
        }
    }
    hf[i] = s * 0.01f;
}

__global__ __launch_bounds__(256)
void final_kernel(const float* __restrict__ x, const float* __restrict__ hf,
                  const float* __restrict__ ft, const float* __restrict__ g,
                  const float* __restrict__ b, const float* __restrict__ m,
                  const float* __restrict__ v, const float* __restrict__ W,
                  const float* __restrict__ bias, float* __restrict__ out)
{
    int bb = blockIdx.x;
    int tid = threadIdx.x;
    float a0 = 0.f, a1 = 0.f;
    for (int c = tid; c < 1536; c += 256) {
        float xv = (c < 512) ? x[bb * 512 + c]
                 : (c < 1024) ? hf[bb * 512 + (c - 512)]
                              : ft[bb * 512 + (c - 1024)];
        float z = (xv - m[c]) * rsqrtf(v[c] + EPSc) * g[c] + b[c];
        a0 += z * W[c];
        a1 += z * W[1536 + c];
    }
    __shared__ float r0[256], r1[256];
    r0[tid] = a0; r1[tid] = a1;
    __syncthreads();
    for (int o = 128; o > 0; o >>= 1) {
        if (tid < o) { r0[tid] += r0[tid + o]; r1[tid] += r1[tid + o]; }
        __syncthreads();
    }
    if (tid == 0) {
        out[bb * 2 + 0] = r0[0] + bias[0];
        out[bb * 2 + 1] = r1[0] + bias[1];
    }
}

// ---------------------------------------------------------------------------
extern "C" void kernel_launch(void* const* d_in, const int* in_sizes, int n_in,
                              void* d_out, int out_size, void* d_ws, size_t ws_size,
                              hipStream_t stream)
{
    (void)in_sizes; (void)n_in; (void)out_size; (void)ws_size;

    const float* img   = (const float*)d_in[0];
    const float* ftxt  = (const float*)d_in[1];
    const float* unixe = (const float*)d_in[2];
    const float* pos   = (const float*)d_in[3];
    const int*   src   = (const int*)  d_in[4];
    const int*   dst   = (const int*)  d_in[5];
    const float* g1W   = (const float*)d_in[6];
    const float* g1al  = (const float*)d_in[7];
    const float* g1ar  = (const float*)d_in[8];
    const float* g1b   = (const float*)d_in[9];
    const float* g2W   = (const float*)d_in[10];
    const float* g2al  = (const float*)d_in[11];
    const float* g2ar  = (const float*)d_in[12];
    const float* g2b   = (const float*)d_in[13];
    const float* fcW   = (const float*)d_in[14];
    const float* fcb   = (const float*)d_in[15];
    const float* hidW  = (const float*)d_in[16];
    const float* hidb  = (const float*)d_in[17];
    const float* btg   = (const float*)d_in[18];
    const float* btb   = (const float*)d_in[19];
    const float* btm   = (const float*)d_in[20];
    const float* btv   = (const float*)d_in[21];
    const float* ftW   = (const float*)d_in[22];
    const float* ftbi  = (const float*)d_in[23];
    const float* swg   = (const float*)d_in[24];
    const float* swb   = (const float*)d_in[25];
    const float* swm   = (const float*)d_in[26];
    const float* swv   = (const float*)d_in[27];
    const float* swW   = (const float*)d_in[28];
    const float* swbi  = (const float*)d_in[29];
    const float* bgg   = (const float*)d_in[30];
    const float* bgb   = (const float*)d_in[31];
    const float* bgm   = (const float*)d_in[32];
    const float* bgv   = (const float*)d_in[33];
    const float* fgW   = (const float*)d_in[34];
    const float* fgb   = (const float*)d_in[35];
    const float* bbgp  = (const float*)d_in[36];
    const float* bbbp  = (const float*)d_in[37];
    const float* bbmp  = (const float*)d_in[38];
    const float* bbvp  = (const float*)d_in[39];
    const float* fbW   = (const float*)d_in[40];
    const float* fbb   = (const float*)d_in[41];
    const float* fng   = (const float*)d_in[42];
    const float* fnb   = (const float*)d_in[43];
    const float* fnm   = (const float*)d_in[44];
    const float* fnv   = (const float*)d_in[45];
    const float* fiW   = (const float*)d_in[46];
    const float* fib   = (const float*)d_in[47];
    float* out = (float*)d_out;

    // ---- workspace layout ----
    char* p = (char*)d_ws;
    unsigned short* fA  = (unsigned short*)p; p += (size_t)Ng * HDd * 2;
    unsigned short* fB  = (unsigned short*)p; p += (size_t)Ng * HDd * 2;
    unsigned short* fC  = (unsigned short*)p; p += (size_t)Ng * Dd * 2;
    unsigned short* fD  = (unsigned short*)p; p += (size_t)Ng * Dd * 2;
    float*          fE  = (float*)p;          p += (size_t)Ng * 480 * 4;
    float*          el  = (float*)p;          p += (size_t)Ng * Hh * 4;
    float*          er  = (float*)p;          p += (size_t)Ng * Hh * 4;
    float*          xb  = (float*)p;          p += (size_t)Bg * Dd * 4;
    float*          ftb = (float*)p;          p += (size_t)Bg * Dd * 4;
    float*          hf  = (float*)p;          p += (size_t)Bg * Dd * 4;
    float*          ti  = (float*)p;          p += (size_t)Bg * IMGd * 4;
    float*          tt  = (float*)p;          p += (size_t)Bg * EMBd * 4;
    unsigned short* ubf = (unsigned short*)p; p += (size_t)Ng * EMBd * 2;
    unsigned short* wg1 = (unsigned short*)p; p += (size_t)HDd * EMBd * 2;
    unsigned short* wg2 = (unsigned short*)p; p += (size_t)HDd * HDd * 2;
    unsigned short* wfc = (unsigned short*)p; p += (size_t)Dd * HDd * 2;
    unsigned short* whid= (unsigned short*)p; p += (size_t)8 * Dd * Dd * 2;
    unsigned short* wfg = (unsigned short*)p; p += (size_t)480 * Dd * 2;
    int* counts = (int*)p; p += (size_t)Ng * 4;
    int* offs   = (int*)p; p += (size_t)(Ng + 1) * 4 + 12;
    int* cursor = (int*)p; p += (size_t)Ng * 4;
    int* eid    = (int*)p; p += (size_t)Eg * 4;

    // ---- merged fp32 -> bf16 conversions ----
    CvtPack cp;
    cp.s[0] = unixe; cp.d[0] = ubf;  cp.n4[0] = Ng * EMBd / 4;
    cp.s[1] = g1W;   cp.d[1] = wg1;  cp.n4[1] = HDd * EMBd / 4;
    cp.s[2] = g2W;   cp.d[2] = wg2;  cp.n4[2] = HDd * HDd / 4;
    cp.s[3] = fcW;   cp.d[3] = wfc;  cp.n4[3] = Dd * HDd / 4;
    cp.s[4] = hidW;  cp.d[4] = whid; cp.n4[4] = 8 * Dd * Dd / 4;
    cp.s[5] = fgW;   cp.d[5] = wfg;  cp.n4[5] = 480 * Dd / 4;
    int total4 = cp.n4[0] + cp.n4[1] + cp.n4[2] + cp.n4[3] + cp.n4[4] + cp.n4[5];
    cvt_all<<<(total4 + 255)/256, 256, 0, stream>>>(cp, total4);

    // ---- image / text branches (fp32, tiny) ----
    bn_col<<<(Bg*IMGd + 255)/256, 256, 0, stream>>>(img, swg, swb, swm, swv, ti, Bg, IMGd);
    gemm_nt<<<dim3(8, 1), 256, 0, stream>>>(ti, swW, swbi, xb, Bg, Dd, IMGd, 1);
    bn_col<<<(Bg*EMBd + 255)/256, 256, 0, stream>>>(ftxt, btg, btb, btm, btv, tt, Bg, EMBd);
    gemm_nt<<<dim3(8, 1), 256, 0, stream>>>(tt, ftW, ftbi, ftb, Bg, Dd, EMBd, 1);

    // ---- CSR by dst ----
    zero_i32<<<(Ng + 255)/256, 256, 0, stream>>>(counts, Ng);
    count_dst<<<(Eg + 255)/256, 256, 0, stream>>>(dst, counts, Eg);
    scan_excl<<<1, 1024, 0, stream>>>(counts, offs, cursor, Ng);
    scatter_edges<<<(Eg + 255)/256, 256, 0, stream>>>(dst, cursor, eid, Eg);

    // ---- GAT layer 1 ----
    gemm_bf16<<<dim3(HDd/128, Ng/128), 256, 0, stream>>>(ubf, wg1, nullptr, fA, Ng, HDd, EMBd, 0, 1);
    elr_kernel<<<Ng, 256, 0, stream>>>(fA, g1al, g1ar, el, er);
    gat_agg<<<Ng, 256, 0, stream>>>(fA, el, er, src, offs, eid, g1b, fB);

    // ---- GAT layer 2 ----
    gemm_bf16<<<dim3(HDd/128, Ng/128), 256, 0, stream>>>(fB, wg2, nullptr, fA, Ng, HDd, HDd, 0, 1);
    elr_kernel<<<Ng, 256, 0, stream>>>(fA, g2al, g2ar, el, er);
    gat_agg<<<Ng, 256, 0, stream>>>(fA, el, er, src, offs, eid, g2b, fB);

    // ---- fc: [6400,2048] -> [6400,512], elu ----
    gemm_bf16_t64<<<dim3(Dd/64, Ng/64), 256, 0, stream>>>(fB, wfc, fcb, fC, Ng, Dd, HDd, 1, 1);

    // ---- 8 hidden layers, ping-pong fC<->fD ----
    unsigned short* cur = fC; unsigned short* nxt = fD;
    for (int i = 0; i < 8; ++i) {
        gemm_bf16_t64<<<dim3(Dd/64, Ng/64), 256, 0, stream>>>(
            cur, whid + (size_t)i * Dd * Dd, hidb + (size_t)i * Dd, nxt, Ng, Dd, Dd, 1, 1);
        unsigned short* t = cur; cur = nxt; nxt = t;
    }
    // result in fC

    // ---- BN over node position, then fc_gat -> [6400,480] f32 ----
    bn_node_b4<<<(Ng*Dd/4 + 255)/256, 256, 0, stream>>>(
        (const ushort4*)cur, bgg, bgb, bgm, bgv, (ushort4*)nxt, Ng*Dd/4, Dd/4);
    gemm_bf16_t64<<<dim3(8, Ng/64), 256, 0, stream>>>(nxt, wfg, fgb, fE, Ng, 480, Dd, 1, 0);

    // ---- mean (pos branch fused) -> hf[64,512] ----
    mean_kernel<<<(Bg*Dd + 255)/256, 256, 0, stream>>>(fE, pos, bbgp, bbbp, bbmp, bbvp, fbW, fbb, hf);

    // ---- final BN + linear -> out[64,2] ----
    final_kernel<<<Bg, 256, 0, stream>>>(xb, hf, ftb, fng, fnb, fnm, fnv, fiW, fib, out);
}